// Round 9
// baseline (429.192 us; speedup 1.0000x reference)
//
#include <hip/hip_runtime.h>
#include <hip/hip_bf16.h>

#ifndef MIN
#define MIN(a,b) ((a)<(b)?(a):(b))
#endif

typedef _Float16 half2_t __attribute__((ext_vector_type(2)));
typedef _Float16 half4_t __attribute__((ext_vector_type(4)));
typedef _Float16 half8_t __attribute__((ext_vector_type(8)));
typedef float floatx4 __attribute__((ext_vector_type(4)));

#define BUCKET_SHIFT 6
#define BUCKET_SIZE 64
#define SCHUNK 2048

// ---------------------------------------------------------------------------
// MFMA f16 GEMM body, BN=64 (4 output col-tiles), 17KB LDS -> ~8 blocks/CU.
// A direct global->VGPR, W staged in LDS. Column-split doubles resident waves.
// SCALE: multiply (acc+bias) by dinv[row] before store (pre-scaled H' rows).
// PLANES: write f16 output in channel-plane layout [4][(M+1)][32] so the
// aggregation's 32-ch slices are contiguous 3.2MB regions (XCD-L2-resident).
// ---------------------------------------------------------------------------

template <int KCH, bool A_F16, bool RELU, bool BIAS, bool SCALE, bool F16OUT, bool PLANES>
__device__ __forceinline__
void gemm_body64(int rb, int ch, const void* __restrict__ Av, int lda,
                 const _Float16* __restrict__ W, int ldw,
                 const float* __restrict__ bias, const float* __restrict__ dinv,
                 void* __restrict__ Cv, int ldc, int M) {
    __shared__ __align__(16) _Float16 Ws[64][136];

    int tid = threadIdx.x;
    int rowBase = rb * 64;
    int colBase = ch * 64;
    int w = tid >> 6;
    int lane = tid & 63;
    int lrow = lane & 15;
    int quad = lane >> 4;
    int kq = quad * 8;
    int gr = rowBase + w * 16 + lrow;

    floatx4 acc[4];
#pragma unroll
    for (int nt = 0; nt < 4; ++nt) acc[nt] = (floatx4){0.f, 0.f, 0.f, 0.f};

#pragma unroll
    for (int kc = 0; kc < KCH; ++kc) {
        // stage W chunk [64 x 128] for this column tile
#pragma unroll
        for (int i = tid; i < 64 * 16; i += 256) {
            int n = i >> 4, k8 = (i & 15) * 8;
            uint4 v = *(const uint4*)(W + (size_t)(colBase + n) * ldw + kc * 128 + k8);
            *(uint4*)(&Ws[n][k8]) = v;
        }
        __syncthreads();

        // A fragments: direct global loads, 16 rows x 64B per wave
        half8_t a[4];
        if (gr < M) {
            if (A_F16) {
                const _Float16* A = (const _Float16*)Av;
                const _Float16* ap = A + (size_t)gr * lda + kc * 128 + kq;
#pragma unroll
                for (int ks = 0; ks < 4; ++ks)
                    a[ks] = *(const half8_t*)(ap + ks * 32);
            } else {
                const float* A = (const float*)Av;
                const float* ap = A + (size_t)gr * lda + kc * 128 + kq;
#pragma unroll
                for (int ks = 0; ks < 4; ++ks) {
                    float4 v0 = *(const float4*)(ap + ks * 32);
                    float4 v1 = *(const float4*)(ap + ks * 32 + 4);
                    half8_t h;
                    h[0] = (_Float16)v0.x; h[1] = (_Float16)v0.y;
                    h[2] = (_Float16)v0.z; h[3] = (_Float16)v0.w;
                    h[4] = (_Float16)v1.x; h[5] = (_Float16)v1.y;
                    h[6] = (_Float16)v1.z; h[7] = (_Float16)v1.w;
                    a[ks] = h;
                }
            }
        } else {
#pragma unroll
            for (int ks = 0; ks < 4; ++ks)
                a[ks] = (half8_t){0, 0, 0, 0, 0, 0, 0, 0};
        }

#pragma unroll
        for (int ks = 0; ks < 4; ++ks) {
            int kk = ks * 32 + kq;
#pragma unroll
            for (int nt = 0; nt < 4; ++nt) {
                half8_t b = *(const half8_t*)(&Ws[nt * 16 + lrow][kk]);
                acc[nt] = __builtin_amdgcn_mfma_f32_16x16x32_f16(a[ks], b, acc[nt], 0, 0, 0);
            }
        }
        if (kc != KCH - 1) __syncthreads();
    }

#pragma unroll
    for (int nt = 0; nt < 4; ++nt) {
        int col = colBase + nt * 16 + lrow;
        float bv = BIAS ? bias[col] : 0.0f;
#pragma unroll
        for (int reg = 0; reg < 4; ++reg) {
            int gr2 = rowBase + w * 16 + quad * 4 + reg;
            if (gr2 < M) {
                float v = acc[nt][reg] + bv;
                if (RELU) v = fmaxf(v, 0.0f);
                if (SCALE) v *= dinv[gr2];
                if (PLANES) {
                    _Float16* C = (_Float16*)Cv;
                    int p = col >> 5, cc = col & 31;
                    C[((size_t)p * (M + 1) + gr2) * 32 + cc] = (_Float16)v;
                } else if (F16OUT) {
                    _Float16* C = (_Float16*)Cv;
                    C[(size_t)gr2 * ldc + col] = (_Float16)v;
                } else {
                    float* C = (float*)Cv;
                    C[(size_t)gr2 * ldc + col] = v;
                }
            }
        }
    }
}

template <int KCH, bool A_F16, bool RELU, bool BIAS, bool SCALE, bool F16OUT, bool PLANES,
          bool SPLIT>
__global__ __launch_bounds__(256)
void mfma_gemm64(const void* __restrict__ Av, int lda,
                 const _Float16* __restrict__ W, int ldw,
                 const float* __restrict__ bias, const float* __restrict__ dinv,
                 void* __restrict__ Cv, int ldc, int M) {
    int rb, ch;
    if (SPLIT) { rb = blockIdx.x >> 1; ch = blockIdx.x & 1; }
    else       { rb = blockIdx.x;      ch = 0; }
    gemm_body64<KCH, A_F16, RELU, BIAS, SCALE, F16OUT, PLANES>(
        rb, ch, Av, lda, W, ldw, bias, dinv, Cv, ldc, M);
}

// ---------------------------------------------------------------------------
// K1: blocks [0,512) = dst histogram into buckets; blocks [512,768) = weight
// fp32->f16 conversion + zeroing of all 4 plane pad rows (row N of each).
// ---------------------------------------------------------------------------

__global__ __launch_bounds__(256)
void k_hist_cvt(const int* __restrict__ dst, int E, int* __restrict__ bucketCnt, int NB,
                const float* __restrict__ a, _Float16* __restrict__ oa, int na,
                const float* __restrict__ b, _Float16* __restrict__ ob, int nb,
                const float* __restrict__ c, _Float16* __restrict__ oc, int nc,
                _Float16* __restrict__ planes, int N) {
    __shared__ int h[1024];
    int t = threadIdx.x;
    if (blockIdx.x < 512) {
        for (int i = t; i < 1024; i += 256) h[i] = 0;
        __syncthreads();
        for (int e = blockIdx.x * 256 + t; e < E; e += 512 * 256)
            atomicAdd(&h[dst[e] >> BUCKET_SHIFT], 1);
        __syncthreads();
        for (int i = t; i < NB; i += 256)
            if (h[i]) atomicAdd(&bucketCnt[i], h[i]);   // no return use -> pipelined
    } else {
        int i = (blockIdx.x - 512) * 256 + t;
        if (i < na) oa[i] = (_Float16)a[i];
        if (i < nb) ob[i] = (_Float16)b[i];
        if (i < nc) oc[i] = (_Float16)c[i];
        if (i < 128) {   // pad row N of each 32-ch plane = 0
            int p = i >> 5, cc = i & 31;
            planes[((size_t)p * (N + 1) + N) * 32 + cc] = (_Float16)0.0f;
        }
    }
}

// one block, 1024 threads: exclusive scan of bucket counts (NB <= 1024)
__global__ void bucket_scan(const int* __restrict__ bucketCnt,
                            int* __restrict__ bucketBase, int* __restrict__ bucketCur,
                            int NB, int E) {
    __shared__ int sm[1024];
    int t = threadIdx.x;
    int v = (t < NB) ? bucketCnt[t] : 0;
    sm[t] = v;
    __syncthreads();
    for (int off = 1; off < 1024; off <<= 1) {
        int add = (t >= off) ? sm[t - off] : 0;
        __syncthreads();
        sm[t] += add;
        __syncthreads();
    }
    if (t < NB) {
        bucketBase[t] = sm[t] - v;
        bucketCur[t] = sm[t] - v;
    }
    if (t == 0) bucketBase[NB] = E;
}

// ---------------------------------------------------------------------------
// K3: blocks [0,SB) = two-level scatter of packed edge records; blocks
// [SB,...) = input-projection GEMM (column-split, independent of CSR chain).
// ---------------------------------------------------------------------------

__global__ __launch_bounds__(256)
void k_scatter_proj(const int* __restrict__ src, const int* __restrict__ dst, int E,
                    int* __restrict__ bucketCur, unsigned int* __restrict__ rec, int SB,
                    const float* __restrict__ A, const _Float16* __restrict__ W,
                    const float* __restrict__ bias, _Float16* __restrict__ Cout, int M) {
    __shared__ int hist[1024];
    __shared__ int base[1024];
    if (blockIdx.x < SB) {
        int t = threadIdx.x;
        int e0 = blockIdx.x * SCHUNK;
        int e1 = MIN(E, e0 + SCHUNK);
        for (int i = t; i < 1024; i += 256) hist[i] = 0;
        __syncthreads();
        for (int e = e0 + t; e < e1; e += 256)
            atomicAdd(&hist[dst[e] >> BUCKET_SHIFT], 1);
        __syncthreads();
        for (int i = t; i < 1024; i += 256) {
            int c = hist[i];
            base[i] = c ? atomicAdd(&bucketCur[i], c) : 0;
            hist[i] = 0;                                  // reuse as local cursor
        }
        __syncthreads();
        for (int e = e0 + t; e < e1; e += 256) {
            int d = dst[e];
            int bk = d >> BUCKET_SHIFT;
            int pos = base[bk] + atomicAdd(&hist[bk], 1); // LDS atomic, cheap
            rec[pos] = (unsigned)src[e] | ((unsigned)(d & (BUCKET_SIZE - 1)) << 16);
        }
    } else {
        int b2 = blockIdx.x - SB;
        gemm_body64<1, false, true, true, false, true, false>(
            b2 >> 1, b2 & 1, A, 128, W, 128, bias, nullptr, Cout, 128, M);
    }
}

// Pass C: one block per bucket — per-node degree, local scan, rowptr/dinv/csr fill
__global__ void bucket_build(const unsigned int* __restrict__ rec,
                             const int* __restrict__ bucketBase,
                             int* __restrict__ rowptr, unsigned short* __restrict__ csr_src,
                             float* __restrict__ dinv, int N, int E) {
    __shared__ int lcnt[256];   // only [0,64) used; padded for uniform scan
    __shared__ int sm[256];
    __shared__ int lcur[64];
    int b = blockIdx.x;
    int t = threadIdx.x;
    int beg = bucketBase[b], end = bucketBase[b + 1];
    lcnt[t] = 0;
    __syncthreads();
    for (int i = beg + t; i < end; i += 256)
        atomicAdd(&lcnt[rec[i] >> 16], 1);
    __syncthreads();
    int v = lcnt[t];
    sm[t] = v;
    __syncthreads();
    for (int off = 1; off < 256; off <<= 1) {
        int add = (t >= off) ? sm[t - off] : 0;
        __syncthreads();
        sm[t] += add;
        __syncthreads();
    }
    int excl = sm[t] - v;
    if (t < BUCKET_SIZE) {
        int node = b * BUCKET_SIZE + t;
        if (node < N) {
            rowptr[node] = beg + excl;
            dinv[node] = rsqrtf((float)(v + 1));   // self loop -> deg >= 1
        }
        lcur[t] = beg + excl;
    }
    __syncthreads();
    for (int i = beg + t; i < end; i += 256) {
        unsigned int r = rec[i];
        int pos = atomicAdd(&lcur[r >> 16], 1);
        csr_src[pos] = (unsigned short)(r & 0xFFFFu);
    }
    if (b == 0 && t == 0) rowptr[N] = E;
}

// ---------------------------------------------------------------------------
// Channel-sliced aggregation over plane layout H'[4][(N+1)][32] (pre-scaled
// rows, pad row N = zeros):
//   X[node] = relu( dinv[node] * ( H'[node] + sum_{s in nbr} H'[s] ) )
// Grid = 4 pass segments x 12500 node-blocks (pass-major): all resident
// blocks of a pass gather from ONE 3.2MB plane -> XCD-L2-resident gathers
// instead of 6.1TB/s fabric misses. Per instruction a wave gathers FOUR
// 64B row-slices (lane group g = t>>4 -> row s[j+4k+g], chunk c = t&15);
// per-layer instruction totals identical to the proven R2 kernel.
// ---------------------------------------------------------------------------

__global__ __launch_bounds__(256)
void agg_kernel(const half2_t* __restrict__ Hp, const float* __restrict__ dinv,
                const int* __restrict__ rowptr,
                const unsigned short* __restrict__ csr_src,
                half2_t* __restrict__ X, int N, int NBLK) {
    int pass = blockIdx.x / NBLK;
    int nb = blockIdx.x - pass * NBLK;
    int node = nb * 4 + (threadIdx.x >> 6);
    int t = threadIdx.x & 63;
    if (node >= N) return;
    int g = t >> 4;      // lane group: which of 4 rows this lane helps gather
    int c = t & 15;      // half2 chunk within the 32-ch slice
    const half2_t* P = Hp + (size_t)pass * (N + 1) * 16;
    float di = dinv[node];
    int beg = rowptr[node];
    int end = rowptr[node + 1];

    // self row: group 0 gathers it; groups 1-3 hit the zero pad row (adds 0)
    int selfs = (g == 0) ? node : N;
    half2_t hu = P[(size_t)selfs * 16 + c];
    float2 acc;
    acc.x = (float)hu.x;
    acc.y = (float)hu.y;

    for (int base = beg; base < end; base += 64) {
        int idx = base + t;
        int s_lane = (idx < end) ? (int)csr_src[idx] : N;   // row N is zeros
        int m = end - base;
        if (m > 64) m = 64;
        int mm = (m + 15) & ~15;                            // pads add 0
        for (int j = 0; j < mm; j += 16) {
            int s0 = __shfl(s_lane, j + g);
            int s1 = __shfl(s_lane, j + 4 + g);
            int s2 = __shfl(s_lane, j + 8 + g);
            int s3 = __shfl(s_lane, j + 12 + g);
            half2_t u0 = P[(size_t)s0 * 16 + c];
            half2_t u1 = P[(size_t)s1 * 16 + c];
            half2_t u2 = P[(size_t)s2 * 16 + c];
            half2_t u3 = P[(size_t)s3 * 16 + c];
            acc.x += (float)u0.x; acc.y += (float)u0.y;
            acc.x += (float)u1.x; acc.y += (float)u1.y;
            acc.x += (float)u2.x; acc.y += (float)u2.y;
            acc.x += (float)u3.x; acc.y += (float)u3.y;
        }
    }

    // combine the 4 lane groups (same chunk c at t, t^16, t^32, t^48)
    acc.x += __shfl_xor(acc.x, 16);
    acc.x += __shfl_xor(acc.x, 32);
    acc.y += __shfl_xor(acc.y, 16);
    acc.y += __shfl_xor(acc.y, 32);

    if (g == 0) {
        half2_t o;
        o.x = (_Float16)fmaxf(acc.x * di, 0.0f);
        o.y = (_Float16)fmaxf(acc.y * di, 0.0f);
        X[(size_t)node * 256 + pass * 16 + c] = o;   // cols pass*32 .. +31
    }
}

// ---------------------------------------------------------------------------
// launch
// ---------------------------------------------------------------------------

extern "C" void kernel_launch(void* const* d_in, const int* in_sizes, int n_in,
                              void* d_out, int out_size, void* d_ws, size_t ws_size,
                              hipStream_t stream) {
    const float* x     = (const float*)d_in[0];
    const int*   ei    = (const int*)d_in[1];
    const float* W_in  = (const float*)d_in[2];
    const float* b_in  = (const float*)d_in[3];
    const float* Wc    = (const float*)d_in[4];
    const float* bc    = (const float*)d_in[5];
    const float* W_out = (const float*)d_in[6];
    const float* b_out = (const float*)d_in[7];
    float* out = (float*)d_out;

    const int HID = 128;
    const int N = in_sizes[0] / HID;   // 50000
    const int E = in_sizes[1] / 2;     // 800000
    const int L = 4;
    const int* src = ei;
    const int* dst = ei + E;
    const int NB = (N + BUCKET_SIZE - 1) >> BUCKET_SHIFT;   // 782

    char* ws = (char*)d_ws;
    size_t off = 0;
    auto carve = [&](size_t bytes) {
        void* p = ws + off;
        off += (bytes + 255) & ~(size_t)255;
        return p;
    };
    float* dinv        = (float*)carve((size_t)N * 4);
    int*   rowptr      = (int*)carve((size_t)(N + 1) * 4);
    unsigned short* csr_src = (unsigned short*)carve((size_t)E * 2);
    unsigned int* rec  = (unsigned int*)carve((size_t)E * 4);
    int*   bucketCnt   = (int*)carve((size_t)1024 * 4);
    int*   bucketBase  = (int*)carve((size_t)1025 * 4);
    int*   bucketCur   = (int*)carve((size_t)1024 * 4);
    _Float16* bufA     = (_Float16*)carve((size_t)N * HID * 2);          // proj output
    _Float16* bufHpl   = (_Float16*)carve((size_t)4 * (N + 1) * 32 * 2); // H' planes
    _Float16* bufXcat  = (_Float16*)carve((size_t)N * 512 * 2);          // concat [N,512]
    _Float16* Wf_in    = (_Float16*)carve((size_t)HID * HID * 2);
    _Float16* Wf_c     = (_Float16*)carve((size_t)L * HID * HID * 2);
    _Float16* Wf_out   = (_Float16*)carve((size_t)64 * 512 * 2);
    (void)ws_size;

    int gemm_blocks = (N + 63) / 64;           // 782 row-blocks
    int SB = (E + SCHUNK - 1) / SCHUNK;        // 391
    int NBLK = (N + 3) / 4;                    // 12500 agg node-blocks per pass

    // ---- CSR build overlapped with weight-cvt + input projection ----
    hipMemsetAsync(bucketCnt, 0, (size_t)1024 * 4, stream);
    k_hist_cvt<<<512 + 256, 256, 0, stream>>>(
        dst, E, bucketCnt, NB,
        W_in, Wf_in, HID * HID,
        Wc, Wf_c, L * HID * HID,
        W_out, Wf_out, 64 * 512,
        bufHpl, N);
    bucket_scan<<<1, 1024, 0, stream>>>(bucketCnt, bucketBase, bucketCur, NB, E);
    k_scatter_proj<<<SB + 2 * gemm_blocks, 256, 0, stream>>>(
        src, dst, E, bucketCur, rec, SB,
        x, Wf_in, b_in, bufA, N);
    bucket_build<<<NB, 256, 0, stream>>>(rec, bucketBase, rowptr, csr_src, dinv, N, E);

    // ---- conv layers; aggregated X goes into bufXcat[:, l*128] ----
    for (int l = 0; l < L; ++l) {
        const void* Ain = (l == 0) ? (const void*)bufA
                                   : (const void*)(bufXcat + (size_t)(l - 1) * 128);
        int lda = (l == 0) ? 128 : 512;
        // H' planes = dinv[row] * (A @ Wc^T + bc)   (f16, plane layout)
        mfma_gemm64<1, true, false, true, true, true, true, true>
            <<<2 * gemm_blocks, 256, 0, stream>>>(Ain, lda, Wf_c + (size_t)l * HID * HID,
                                                  HID, bc + (size_t)l * HID, dinv,
                                                  bufHpl, 0, N);
        agg_kernel<<<4 * NBLK, 256, 0, stream>>>((const half2_t*)bufHpl, dinv, rowptr,
                                                 csr_src,
                                                 (half2_t*)bufXcat + (size_t)l * 64,
                                                 N, NBLK);
    }

    // ---- single concatenated output GEMM: out = bufXcat @ W_out^T + b_out ----
    mfma_gemm64<4, true, false, true, false, false, false, false>
        <<<gemm_blocks, 256, 0, stream>>>(bufXcat, 512, Wf_out, 512, b_out, nullptr,
                                          out, 64, N);
}

// Round 10
// 348.228 us; speedup vs baseline: 1.2325x; 1.2325x over previous
//
#include <hip/hip_runtime.h>
#include <hip/hip_bf16.h>

#ifndef MIN
#define MIN(a,b) ((a)<(b)?(a):(b))
#endif

typedef _Float16 half2_t __attribute__((ext_vector_type(2)));
typedef _Float16 half4_t __attribute__((ext_vector_type(4)));
typedef _Float16 half8_t __attribute__((ext_vector_type(8)));
typedef float floatx4 __attribute__((ext_vector_type(4)));

#define BUCKET_SHIFT 6
#define BUCKET_SIZE 64
#define SCHUNK 2048

// ---------------------------------------------------------------------------
// MFMA f16 GEMM body, BN=64 col-tiles (ch selects cols), rbOff for row-half
// dispatch. A-fragment loads ISSUED BEFORE W staging (independent of LDS) so
// their latency hides under the stage+barrier. A direct global->VGPR, W in LDS.
// SCALE: multiply (acc+bias) by dinv[row] before store (pre-scaled H' rows).
// ---------------------------------------------------------------------------

template <int KCH, bool A_F16, bool RELU, bool BIAS, bool SCALE, bool F16OUT>
__device__ __forceinline__
void gemm_body64(int rb, int ch, const void* __restrict__ Av, int lda,
                 const _Float16* __restrict__ W, int ldw,
                 const float* __restrict__ bias, const float* __restrict__ dinv,
                 void* __restrict__ Cv, int ldc, int M) {
    __shared__ __align__(16) _Float16 Ws[64][136];

    int tid = threadIdx.x;
    int rowBase = rb * 64;
    int colBase = ch * 64;
    int w = tid >> 6;
    int lane = tid & 63;
    int lrow = lane & 15;
    int quad = lane >> 4;
    int kq = quad * 8;
    int gr = rowBase + w * 16 + lrow;

    floatx4 acc[4];
#pragma unroll
    for (int nt = 0; nt < 4; ++nt) acc[nt] = (floatx4){0.f, 0.f, 0.f, 0.f};

#pragma unroll
    for (int kc = 0; kc < KCH; ++kc) {
        // A fragments FIRST (no LDS dependency -> latency overlaps W staging)
        half8_t a[4];
        if (gr < M) {
            if (A_F16) {
                const _Float16* A = (const _Float16*)Av;
                const _Float16* ap = A + (size_t)gr * lda + kc * 128 + kq;
#pragma unroll
                for (int ks = 0; ks < 4; ++ks)
                    a[ks] = *(const half8_t*)(ap + ks * 32);
            } else {
                const float* A = (const float*)Av;
                const float* ap = A + (size_t)gr * lda + kc * 128 + kq;
#pragma unroll
                for (int ks = 0; ks < 4; ++ks) {
                    float4 v0 = *(const float4*)(ap + ks * 32);
                    float4 v1 = *(const float4*)(ap + ks * 32 + 4);
                    half8_t h;
                    h[0] = (_Float16)v0.x; h[1] = (_Float16)v0.y;
                    h[2] = (_Float16)v0.z; h[3] = (_Float16)v0.w;
                    h[4] = (_Float16)v1.x; h[5] = (_Float16)v1.y;
                    h[6] = (_Float16)v1.z; h[7] = (_Float16)v1.w;
                    a[ks] = h;
                }
            }
        } else {
#pragma unroll
            for (int ks = 0; ks < 4; ++ks)
                a[ks] = (half8_t){0, 0, 0, 0, 0, 0, 0, 0};
        }

        // stage W chunk [64 x 128] for this column tile
#pragma unroll
        for (int i = tid; i < 64 * 16; i += 256) {
            int n = i >> 4, k8 = (i & 15) * 8;
            uint4 v = *(const uint4*)(W + (size_t)(colBase + n) * ldw + kc * 128 + k8);
            *(uint4*)(&Ws[n][k8]) = v;
        }
        __syncthreads();

#pragma unroll
        for (int ks = 0; ks < 4; ++ks) {
            int kk = ks * 32 + kq;
#pragma unroll
            for (int nt = 0; nt < 4; ++nt) {
                half8_t b = *(const half8_t*)(&Ws[nt * 16 + lrow][kk]);
                acc[nt] = __builtin_amdgcn_mfma_f32_16x16x32_f16(a[ks], b, acc[nt], 0, 0, 0);
            }
        }
        if (kc != KCH - 1) __syncthreads();
    }

#pragma unroll
    for (int nt = 0; nt < 4; ++nt) {
        int col = colBase + nt * 16 + lrow;
        float bv = BIAS ? bias[col] : 0.0f;
#pragma unroll
        for (int reg = 0; reg < 4; ++reg) {
            int gr2 = rowBase + w * 16 + quad * 4 + reg;
            if (gr2 < M) {
                float v = acc[nt][reg] + bv;
                if (RELU) v = fmaxf(v, 0.0f);
                if (SCALE) v *= dinv[gr2];
                if (F16OUT) {
                    _Float16* C = (_Float16*)Cv;
                    C[(size_t)gr2 * ldc + col] = (_Float16)v;
                } else {
                    float* C = (float*)Cv;
                    C[(size_t)gr2 * ldc + col] = v;
                }
            }
        }
    }
}

template <int KCH, bool A_F16, bool RELU, bool BIAS, bool SCALE, bool F16OUT, bool SPLIT>
__global__ __launch_bounds__(256)
void mfma_gemm64(const void* __restrict__ Av, int lda,
                 const _Float16* __restrict__ W, int ldw,
                 const float* __restrict__ bias, const float* __restrict__ dinv,
                 void* __restrict__ Cv, int ldc, int M, int rbOff) {
    int rb, ch;
    if (SPLIT) { rb = (blockIdx.x >> 1) + rbOff; ch = blockIdx.x & 1; }
    else       { rb = blockIdx.x + rbOff;        ch = 0; }
    gemm_body64<KCH, A_F16, RELU, BIAS, SCALE, F16OUT>(
        rb, ch, Av, lda, W, ldw, bias, dinv, Cv, ldc, M);
}

// ---------------------------------------------------------------------------
// Aggregation body (R2/R8 proven form, node-range parameterized):
//   X[node] = relu( dinv[node] * ( H'[node] + sum_{s in nbr} H'[s] ) )
// over pre-scaled rows H' (row N = zeros). 1 wave/node, 1 dword/lane,
// 16 independent row gathers in flight.
// ---------------------------------------------------------------------------

__device__ __forceinline__
void agg_body(int nodeBlk, int lo, const half2_t* __restrict__ Hb,
              const float* __restrict__ dinv, const int* __restrict__ rowptr,
              const unsigned short* __restrict__ csr_src,
              half2_t* __restrict__ X, int N) {
    int node = lo + nodeBlk * 4 + (threadIdx.x >> 6);
    int t = threadIdx.x & 63;
    if (node >= N) return;
    float di = dinv[node];
    half2_t hu = Hb[(size_t)node * 64 + t];
    float2 acc;
    acc.x = (float)hu.x;
    acc.y = (float)hu.y;
    int beg = rowptr[node];
    int end = rowptr[node + 1];

    for (int base = beg; base < end; base += 64) {
        int idx = base + t;
        int s_lane = (idx < end) ? (int)csr_src[idx] : N;   // row N is zeros
        int m = end - base;
        if (m > 64) m = 64;
        int mm = (m + 15) & ~15;                            // pads add 0
        for (int j = 0; j < mm; j += 16) {
            int s[16];
#pragma unroll
            for (int k = 0; k < 16; ++k) s[k] = __shfl(s_lane, j + k);
            half2_t u[16];
#pragma unroll
            for (int k = 0; k < 16; ++k) u[k] = Hb[(size_t)s[k] * 64 + t];
#pragma unroll
            for (int k = 0; k < 16; ++k) {
                acc.x += (float)u[k].x;
                acc.y += (float)u[k].y;
            }
        }
    }
    half2_t o;
    o.x = (_Float16)fmaxf(acc.x * di, 0.0f);
    o.y = (_Float16)fmaxf(acc.y * di, 0.0f);
    X[(size_t)node * 256 + t] = o;   // ld = 512 f16, caller pre-offsets column
}

__global__ __launch_bounds__(256)
void agg_kernel(const half2_t* __restrict__ Hb, const float* __restrict__ dinv,
                const int* __restrict__ rowptr,
                const unsigned short* __restrict__ csr_src,
                half2_t* __restrict__ X, int N, int lo) {
    agg_body(blockIdx.x, lo, Hb, dinv, rowptr, csr_src, X, N);
}

// ---------------------------------------------------------------------------
// Combined dispatch: blocks [0,aggN) run agg(l) on nodes [lo,N); blocks
// [aggN,...) run conv(l+1) row-half (col-split) reading X rows produced by
// the PREVIOUS dispatch (agg h0) — row-local dependency, no race. Conv
// writes the OTHER H buffer (ping-pong) so agg's gathers are undisturbed.
// Agg blocks lead the range so they launch first; conv fills idle CUs.
// ---------------------------------------------------------------------------

__global__ __launch_bounds__(256)
void k_agg_conv(const half2_t* __restrict__ Hin, const float* __restrict__ dinv,
                const int* __restrict__ rowptr,
                const unsigned short* __restrict__ csr_src,
                half2_t* __restrict__ Xslab, int N, int lo, int aggN,
                const _Float16* __restrict__ Ain, int lda,
                const _Float16* __restrict__ W, const float* __restrict__ bias,
                _Float16* __restrict__ Hout, int rbOff) {
    if ((int)blockIdx.x < aggN) {
        agg_body(blockIdx.x, lo, Hin, dinv, rowptr, csr_src, Xslab, N);
    } else {
        int b2 = blockIdx.x - aggN;
        gemm_body64<1, true, false, true, true, true>(
            (b2 >> 1) + rbOff, b2 & 1, Ain, lda, W, 128, bias, dinv, Hout, 128, N);
    }
}

__global__ __launch_bounds__(256)
void k_agg_out(const half2_t* __restrict__ Hin, const float* __restrict__ dinv,
               const int* __restrict__ rowptr,
               const unsigned short* __restrict__ csr_src,
               half2_t* __restrict__ Xslab, int N, int lo, int aggN,
               const _Float16* __restrict__ Xcat,
               const _Float16* __restrict__ W, const float* __restrict__ bias,
               float* __restrict__ out, int rbOff) {
    if ((int)blockIdx.x < aggN) {
        agg_body(blockIdx.x, lo, Hin, dinv, rowptr, csr_src, Xslab, N);
    } else {
        int b2 = blockIdx.x - aggN;
        gemm_body64<4, true, false, true, false, false>(
            b2 + rbOff, 0, Xcat, 512, W, 512, bias, nullptr, out, 64, N);
    }
}

// ---------------------------------------------------------------------------
// K1: blocks [0,512) = dst histogram into buckets; blocks [512,768) = weight
// fp32->f16 conversion + zeroing of both H pad rows (ping-pong buffers).
// ---------------------------------------------------------------------------

__global__ __launch_bounds__(256)
void k_hist_cvt(const int* __restrict__ dst, int E, int* __restrict__ bucketCnt, int NB,
                const float* __restrict__ a, _Float16* __restrict__ oa, int na,
                const float* __restrict__ b, _Float16* __restrict__ ob, int nb,
                const float* __restrict__ c, _Float16* __restrict__ oc, int nc,
                _Float16* __restrict__ zrow1, _Float16* __restrict__ zrow2) {
    __shared__ int h[1024];
    int t = threadIdx.x;
    if (blockIdx.x < 512) {
        for (int i = t; i < 1024; i += 256) h[i] = 0;
        __syncthreads();
        for (int e = blockIdx.x * 256 + t; e < E; e += 512 * 256)
            atomicAdd(&h[dst[e] >> BUCKET_SHIFT], 1);
        __syncthreads();
        for (int i = t; i < NB; i += 256)
            if (h[i]) atomicAdd(&bucketCnt[i], h[i]);   // no return use -> pipelined
    } else {
        int i = (blockIdx.x - 512) * 256 + t;
        if (i < na) oa[i] = (_Float16)a[i];
        if (i < nb) ob[i] = (_Float16)b[i];
        if (i < nc) oc[i] = (_Float16)c[i];
        if (i < 128) { zrow1[i] = (_Float16)0.0f; zrow2[i] = (_Float16)0.0f; }
    }
}

// one block, 1024 threads: exclusive scan of bucket counts (NB <= 1024)
__global__ void bucket_scan(const int* __restrict__ bucketCnt,
                            int* __restrict__ bucketBase, int* __restrict__ bucketCur,
                            int NB, int E) {
    __shared__ int sm[1024];
    int t = threadIdx.x;
    int v = (t < NB) ? bucketCnt[t] : 0;
    sm[t] = v;
    __syncthreads();
    for (int off = 1; off < 1024; off <<= 1) {
        int add = (t >= off) ? sm[t - off] : 0;
        __syncthreads();
        sm[t] += add;
        __syncthreads();
    }
    if (t < NB) {
        bucketBase[t] = sm[t] - v;
        bucketCur[t] = sm[t] - v;
    }
    if (t == 0) bucketBase[NB] = E;
}

// ---------------------------------------------------------------------------
// K3: blocks [0,SB) = two-level scatter of packed edge records; blocks
// [SB,...) = input-projection GEMM (column-split, independent of CSR chain).
// ---------------------------------------------------------------------------

__global__ __launch_bounds__(256)
void k_scatter_proj(const int* __restrict__ src, const int* __restrict__ dst, int E,
                    int* __restrict__ bucketCur, unsigned int* __restrict__ rec, int SB,
                    const float* __restrict__ A, const _Float16* __restrict__ W,
                    const float* __restrict__ bias, _Float16* __restrict__ Cout, int M) {
    __shared__ int hist[1024];
    __shared__ int base[1024];
    if (blockIdx.x < SB) {
        int t = threadIdx.x;
        int e0 = blockIdx.x * SCHUNK;
        int e1 = MIN(E, e0 + SCHUNK);
        for (int i = t; i < 1024; i += 256) hist[i] = 0;
        __syncthreads();
        for (int e = e0 + t; e < e1; e += 256)
            atomicAdd(&hist[dst[e] >> BUCKET_SHIFT], 1);
        __syncthreads();
        for (int i = t; i < 1024; i += 256) {
            int c = hist[i];
            base[i] = c ? atomicAdd(&bucketCur[i], c) : 0;
            hist[i] = 0;                                  // reuse as local cursor
        }
        __syncthreads();
        for (int e = e0 + t; e < e1; e += 256) {
            int d = dst[e];
            int bk = d >> BUCKET_SHIFT;
            int pos = base[bk] + atomicAdd(&hist[bk], 1); // LDS atomic, cheap
            rec[pos] = (unsigned)src[e] | ((unsigned)(d & (BUCKET_SIZE - 1)) << 16);
        }
    } else {
        int b2 = blockIdx.x - SB;
        gemm_body64<1, false, true, true, false, true>(
            b2 >> 1, b2 & 1, A, 128, W, 128, bias, nullptr, Cout, 128, M);
    }
}

// Pass C: one block per bucket — per-node degree, local scan, rowptr/dinv/csr fill
__global__ void bucket_build(const unsigned int* __restrict__ rec,
                             const int* __restrict__ bucketBase,
                             int* __restrict__ rowptr, unsigned short* __restrict__ csr_src,
                             float* __restrict__ dinv, int N, int E) {
    __shared__ int lcnt[256];   // only [0,64) used; padded for uniform scan
    __shared__ int sm[256];
    __shared__ int lcur[64];
    int b = blockIdx.x;
    int t = threadIdx.x;
    int beg = bucketBase[b], end = bucketBase[b + 1];
    lcnt[t] = 0;
    __syncthreads();
    for (int i = beg + t; i < end; i += 256)
        atomicAdd(&lcnt[rec[i] >> 16], 1);
    __syncthreads();
    int v = lcnt[t];
    sm[t] = v;
    __syncthreads();
    for (int off = 1; off < 256; off <<= 1) {
        int add = (t >= off) ? sm[t - off] : 0;
        __syncthreads();
        sm[t] += add;
        __syncthreads();
    }
    int excl = sm[t] - v;
    if (t < BUCKET_SIZE) {
        int node = b * BUCKET_SIZE + t;
        if (node < N) {
            rowptr[node] = beg + excl;
            dinv[node] = rsqrtf((float)(v + 1));   // self loop -> deg >= 1
        }
        lcur[t] = beg + excl;
    }
    __syncthreads();
    for (int i = beg + t; i < end; i += 256) {
        unsigned int r = rec[i];
        int pos = atomicAdd(&lcur[r >> 16], 1);
        csr_src[pos] = (unsigned short)(r & 0xFFFFu);
    }
    if (b == 0 && t == 0) rowptr[N] = E;
}

// ---------------------------------------------------------------------------
// launch
// ---------------------------------------------------------------------------

extern "C" void kernel_launch(void* const* d_in, const int* in_sizes, int n_in,
                              void* d_out, int out_size, void* d_ws, size_t ws_size,
                              hipStream_t stream) {
    const float* x     = (const float*)d_in[0];
    const int*   ei    = (const int*)d_in[1];
    const float* W_in  = (const float*)d_in[2];
    const float* b_in  = (const float*)d_in[3];
    const float* Wc    = (const float*)d_in[4];
    const float* bc    = (const float*)d_in[5];
    const float* W_out = (const float*)d_in[6];
    const float* b_out = (const float*)d_in[7];
    float* out = (float*)d_out;

    const int HID = 128;
    const int N = in_sizes[0] / HID;   // 50000
    const int E = in_sizes[1] / 2;     // 800000
    const int L = 4;
    const int* src = ei;
    const int* dst = ei + E;
    const int NB = (N + BUCKET_SIZE - 1) >> BUCKET_SHIFT;   // 782

    char* ws = (char*)d_ws;
    size_t off = 0;
    auto carve = [&](size_t bytes) {
        void* p = ws + off;
        off += (bytes + 255) & ~(size_t)255;
        return p;
    };
    float* dinv        = (float*)carve((size_t)N * 4);
    int*   rowptr      = (int*)carve((size_t)(N + 1) * 4);
    unsigned short* csr_src = (unsigned short*)carve((size_t)E * 2);
    unsigned int* rec  = (unsigned int*)carve((size_t)E * 4);
    int*   bucketCnt   = (int*)carve((size_t)1024 * 4);
    int*   bucketBase  = (int*)carve((size_t)1025 * 4);
    int*   bucketCur   = (int*)carve((size_t)1024 * 4);
    _Float16* bufA     = (_Float16*)carve((size_t)N * HID * 2);          // proj output
    _Float16* bufHa    = (_Float16*)carve((size_t)(N + 1) * HID * 2);    // H ping + pad
    _Float16* bufHb    = (_Float16*)carve((size_t)(N + 1) * HID * 2);    // H pong + pad
    _Float16* bufXcat  = (_Float16*)carve((size_t)N * 512 * 2);          // concat [N,512]
    _Float16* Wf_in    = (_Float16*)carve((size_t)HID * HID * 2);
    _Float16* Wf_c     = (_Float16*)carve((size_t)L * HID * HID * 2);
    _Float16* Wf_out   = (_Float16*)carve((size_t)64 * 512 * 2);
    (void)ws_size;

    int gemm_blocks = (N + 63) / 64;           // 782 row-blocks (BM=64)
    int SB = (E + SCHUNK - 1) / SCHUNK;        // 391
    int HALF_RB = (gemm_blocks + 1) / 2;       // 391 row-blocks in half 0
    int RB1 = gemm_blocks - HALF_RB;           // 391 row-blocks in half 1
    int HALF = HALF_RB * 64;                   // 25024 rows/nodes in half 0
    int hi0 = MIN(HALF, N);
    int AGG0 = (hi0 + 3) / 4;                  // agg blocks, nodes [0, HALF)
    int AGG1 = (N - hi0 + 3) / 4;              // agg blocks, nodes [HALF, N)

    _Float16* Hbuf[2] = {bufHa, bufHb};

    // ---- CSR build overlapped with weight-cvt + input projection ----
    hipMemsetAsync(bucketCnt, 0, (size_t)1024 * 4, stream);
    k_hist_cvt<<<512 + 256, 256, 0, stream>>>(
        dst, E, bucketCnt, NB,
        W_in, Wf_in, HID * HID,
        Wc, Wf_c, L * HID * HID,
        W_out, Wf_out, 64 * 512,
        bufHa + (size_t)N * HID, bufHb + (size_t)N * HID);
    bucket_scan<<<1, 1024, 0, stream>>>(bucketCnt, bucketBase, bucketCur, NB, E);
    k_scatter_proj<<<SB + 2 * gemm_blocks, 256, 0, stream>>>(
        src, dst, E, bucketCur, rec, SB,
        x, Wf_in, b_in, bufA, N);
    bucket_build<<<NB, 256, 0, stream>>>(rec, bucketBase, rowptr, csr_src, dinv, N, E);

    // ---- conv0 (full): H'(0) = dinv * (bufA @ Wc0^T + bc0) -> bufHa ----
    mfma_gemm64<1, true, false, true, true, true, true>
        <<<2 * gemm_blocks, 256, 0, stream>>>(bufA, 128, Wf_c, 128, bc, dinv,
                                              bufHa, 128, N, 0);

    // ---- pipelined layers: [agg(l)h0] [agg(l)h1 || conv(l+1)h0] [conv(l+1)h1]
    for (int l = 0; l < 3; ++l) {
        const half2_t* Hin = (const half2_t*)Hbuf[l & 1];
        _Float16* Hout = Hbuf[(l + 1) & 1];
        half2_t* Xslab = (half2_t*)bufXcat + (size_t)l * 64;
        const _Float16* Xin = bufXcat + (size_t)l * 128;   // conv(l+1) A input

        agg_kernel<<<AGG0, 256, 0, stream>>>(Hin, dinv, rowptr, csr_src, Xslab, N, 0);
        k_agg_conv<<<AGG1 + 2 * HALF_RB, 256, 0, stream>>>(
            Hin, dinv, rowptr, csr_src, Xslab, N, hi0, AGG1,
            Xin, 512, Wf_c + (size_t)(l + 1) * HID * HID, bc + (size_t)(l + 1) * HID,
            Hout, 0);
        mfma_gemm64<1, true, false, true, true, true, true>
            <<<2 * RB1, 256, 0, stream>>>(Xin, 512,
                                          Wf_c + (size_t)(l + 1) * HID * HID, 128,
                                          bc + (size_t)(l + 1) * HID, dinv,
                                          Hout, 128, N, HALF_RB);
    }

    // ---- tail: [agg3h0] [agg3h1 || out_h0] [out_h1] ----
    {
        const half2_t* Hin = (const half2_t*)Hbuf[3 & 1];   // bufHb
        half2_t* Xslab = (half2_t*)bufXcat + (size_t)3 * 64;

        agg_kernel<<<AGG0, 256, 0, stream>>>(Hin, dinv, rowptr, csr_src, Xslab, N, 0);
        k_agg_out<<<AGG1 + HALF_RB, 256, 0, stream>>>(
            Hin, dinv, rowptr, csr_src, Xslab, N, hi0, AGG1,
            bufXcat, Wf_out, b_out, out, 0);
        mfma_gemm64<4, true, false, true, false, false, false>
            <<<RB1, 256, 0, stream>>>(bufXcat, 512, Wf_out, 512, b_out, nullptr,
                                      out, 64, N, HALF_RB);
    }
}

// Round 11
// 320.150 us; speedup vs baseline: 1.3406x; 1.0877x over previous
//
#include <hip/hip_runtime.h>
#include <hip/hip_bf16.h>

#ifndef MIN
#define MIN(a,b) ((a)<(b)?(a):(b))
#endif

typedef _Float16 half2_t __attribute__((ext_vector_type(2)));
typedef _Float16 half4_t __attribute__((ext_vector_type(4)));
typedef _Float16 half8_t __attribute__((ext_vector_type(8)));
typedef float floatx4 __attribute__((ext_vector_type(4)));

#define BUCKET_SHIFT 6
#define BUCKET_SIZE 64
#define SCHUNK 2048

// ---------------------------------------------------------------------------
// MFMA f16 GEMM body, BN=64 (4 output col-tiles), 17KB LDS -> 8 blocks/CU.
// A direct global->VGPR, W staged in LDS. Column-split (ch) doubles resident
// waves. SCALE: multiply (acc+bias) by dinv[row] (pre-scaled H' rows).
// ACCUM: fp32 read-modify-write into C (K-split partial sums).
// (R8-proven body, unchanged.)
// ---------------------------------------------------------------------------

template <int KCH, bool A_F16, bool RELU, bool BIAS, bool SCALE, bool F16OUT, bool ACCUM>
__device__ __forceinline__
void gemm_body64(int rb, int ch, const void* __restrict__ Av, int lda,
                 const _Float16* __restrict__ W, int ldw,
                 const float* __restrict__ bias, const float* __restrict__ dinv,
                 void* __restrict__ Cv, int ldc, int M) {
    __shared__ __align__(16) _Float16 Ws[64][136];

    int tid = threadIdx.x;
    int rowBase = rb * 64;
    int colBase = ch * 64;
    int w = tid >> 6;
    int lane = tid & 63;
    int lrow = lane & 15;
    int quad = lane >> 4;
    int kq = quad * 8;
    int gr = rowBase + w * 16 + lrow;

    floatx4 acc[4];
#pragma unroll
    for (int nt = 0; nt < 4; ++nt) acc[nt] = (floatx4){0.f, 0.f, 0.f, 0.f};

#pragma unroll
    for (int kc = 0; kc < KCH; ++kc) {
        // stage W chunk [64 x 128] for this column tile
#pragma unroll
        for (int i = tid; i < 64 * 16; i += 256) {
            int n = i >> 4, k8 = (i & 15) * 8;
            uint4 v = *(const uint4*)(W + (size_t)(colBase + n) * ldw + kc * 128 + k8);
            *(uint4*)(&Ws[n][k8]) = v;
        }
        __syncthreads();

        // A fragments: direct global loads, 16 rows x 64B per wave
        half8_t a[4];
        if (gr < M) {
            if (A_F16) {
                const _Float16* A = (const _Float16*)Av;
                const _Float16* ap = A + (size_t)gr * lda + kc * 128 + kq;
#pragma unroll
                for (int ks = 0; ks < 4; ++ks)
                    a[ks] = *(const half8_t*)(ap + ks * 32);
            } else {
                const float* A = (const float*)Av;
                const float* ap = A + (size_t)gr * lda + kc * 128 + kq;
#pragma unroll
                for (int ks = 0; ks < 4; ++ks) {
                    float4 v0 = *(const float4*)(ap + ks * 32);
                    float4 v1 = *(const float4*)(ap + ks * 32 + 4);
                    half8_t h;
                    h[0] = (_Float16)v0.x; h[1] = (_Float16)v0.y;
                    h[2] = (_Float16)v0.z; h[3] = (_Float16)v0.w;
                    h[4] = (_Float16)v1.x; h[5] = (_Float16)v1.y;
                    h[6] = (_Float16)v1.z; h[7] = (_Float16)v1.w;
                    a[ks] = h;
                }
            }
        } else {
#pragma unroll
            for (int ks = 0; ks < 4; ++ks)
                a[ks] = (half8_t){0, 0, 0, 0, 0, 0, 0, 0};
        }

#pragma unroll
        for (int ks = 0; ks < 4; ++ks) {
            int kk = ks * 32 + kq;
#pragma unroll
            for (int nt = 0; nt < 4; ++nt) {
                half8_t b = *(const half8_t*)(&Ws[nt * 16 + lrow][kk]);
                acc[nt] = __builtin_amdgcn_mfma_f32_16x16x32_f16(a[ks], b, acc[nt], 0, 0, 0);
            }
        }
        if (kc != KCH - 1) __syncthreads();
    }

#pragma unroll
    for (int nt = 0; nt < 4; ++nt) {
        int col = colBase + nt * 16 + lrow;
        float bv = BIAS ? bias[col] : 0.0f;
#pragma unroll
        for (int reg = 0; reg < 4; ++reg) {
            int gr2 = rowBase + w * 16 + quad * 4 + reg;
            if (gr2 < M) {
                float v = acc[nt][reg] + bv;
                if (RELU) v = fmaxf(v, 0.0f);
                if (SCALE) v *= dinv[gr2];
                if (F16OUT) {
                    _Float16* C = (_Float16*)Cv;
                    C[(size_t)gr2 * ldc + col] = (_Float16)v;
                } else {
                    float* C = (float*)Cv;
                    if (ACCUM) v += C[(size_t)gr2 * ldc + col];
                    C[(size_t)gr2 * ldc + col] = v;
                }
            }
        }
    }
}

template <int KCH, bool A_F16, bool RELU, bool BIAS, bool SCALE, bool F16OUT, bool ACCUM,
          bool SPLIT>
__global__ __launch_bounds__(256)
void mfma_gemm64(const void* __restrict__ Av, int lda,
                 const _Float16* __restrict__ W, int ldw,
                 const float* __restrict__ bias, const float* __restrict__ dinv,
                 void* __restrict__ Cv, int ldc, int M) {
    int rb, ch;
    if (SPLIT) { rb = blockIdx.x >> 1; ch = blockIdx.x & 1; }
    else       { rb = blockIdx.x;      ch = 0; }
    gemm_body64<KCH, A_F16, RELU, BIAS, SCALE, F16OUT, ACCUM>(
        rb, ch, Av, lda, W, ldw, bias, dinv, Cv, ldc, M);
}

// ---------------------------------------------------------------------------
// Aggregation body (R2/R8 proven form):
//   X[node] = relu( dinv[node] * ( H'[node] + sum_{s in nbr} H'[s] ) )
// over pre-scaled rows H' (row N = zeros). 1 wave/node, 1 dword/lane,
// 16 independent row gathers in flight.
// ---------------------------------------------------------------------------

__device__ __forceinline__
void agg_body(int nodeBlk, const half2_t* __restrict__ Hb,
              const float* __restrict__ dinv, const int* __restrict__ rowptr,
              const unsigned short* __restrict__ csr_src,
              half2_t* __restrict__ X, int N) {
    int node = nodeBlk * 4 + (threadIdx.x >> 6);
    int t = threadIdx.x & 63;
    if (node >= N) return;
    float di = dinv[node];
    half2_t hu = Hb[(size_t)node * 64 + t];
    float2 acc;
    acc.x = (float)hu.x;
    acc.y = (float)hu.y;
    int beg = rowptr[node];
    int end = rowptr[node + 1];

    for (int base = beg; base < end; base += 64) {
        int idx = base + t;
        int s_lane = (idx < end) ? (int)csr_src[idx] : N;   // row N is zeros
        int m = end - base;
        if (m > 64) m = 64;
        int mm = (m + 15) & ~15;                            // pads add 0
        for (int j = 0; j < mm; j += 16) {
            int s[16];
#pragma unroll
            for (int k = 0; k < 16; ++k) s[k] = __shfl(s_lane, j + k);
            half2_t u[16];
#pragma unroll
            for (int k = 0; k < 16; ++k) u[k] = Hb[(size_t)s[k] * 64 + t];
#pragma unroll
            for (int k = 0; k < 16; ++k) {
                acc.x += (float)u[k].x;
                acc.y += (float)u[k].y;
            }
        }
    }
    half2_t o;
    o.x = (_Float16)fmaxf(acc.x * di, 0.0f);
    o.y = (_Float16)fmaxf(acc.y * di, 0.0f);
    X[(size_t)node * 256 + t] = o;   // ld = 512 f16, caller pre-offsets column
}

__global__ __launch_bounds__(256)
void agg_kernel(const half2_t* __restrict__ Hb, const float* __restrict__ dinv,
                const int* __restrict__ rowptr,
                const unsigned short* __restrict__ csr_src,
                half2_t* __restrict__ X, int N) {
    agg_body(blockIdx.x, Hb, dinv, rowptr, csr_src, X, N);
}

// ---------------------------------------------------------------------------
// agg(3) dispatch with trailing INDEPENDENT work: blocks [0,aggN) run agg(3)
// (BW-bound); blocks [aggN,...) run out-partA = Xcat[:,0:384] @ W_out[:,0:384]^T
// + b_out (K-chunks 0-2, whose inputs -- slabs 0..2 -- were completed before
// this dispatch launched; row-local, no dependence on agg(3)). The
// latency-bound GEMM hides under the gather BW (k_scatter_proj pattern).
// ---------------------------------------------------------------------------

__global__ __launch_bounds__(256)
void k_agg_out(const half2_t* __restrict__ Hin, const float* __restrict__ dinv,
               const int* __restrict__ rowptr,
               const unsigned short* __restrict__ csr_src,
               half2_t* __restrict__ Xslab, int N, int aggN,
               const _Float16* __restrict__ Xcat,
               const _Float16* __restrict__ W, const float* __restrict__ bias,
               float* __restrict__ out) {
    if ((int)blockIdx.x < aggN) {
        agg_body(blockIdx.x, Hin, dinv, rowptr, csr_src, Xslab, N);
    } else {
        int b2 = blockIdx.x - aggN;
        gemm_body64<3, true, false, true, false, false, false>(
            b2, 0, Xcat, 512, W, 512, bias, nullptr, out, 64, N);
    }
}

// ---------------------------------------------------------------------------
// K1: blocks [0,512) = dst histogram into buckets; blocks [512,768) = weight
// fp32->f16 conversion + zeroing of bufH pad row N.
// ---------------------------------------------------------------------------

__global__ __launch_bounds__(256)
void k_hist_cvt(const int* __restrict__ dst, int E, int* __restrict__ bucketCnt, int NB,
                const float* __restrict__ a, _Float16* __restrict__ oa, int na,
                const float* __restrict__ b, _Float16* __restrict__ ob, int nb,
                const float* __restrict__ c, _Float16* __restrict__ oc, int nc,
                _Float16* __restrict__ zrow) {
    __shared__ int h[1024];
    int t = threadIdx.x;
    if (blockIdx.x < 512) {
        for (int i = t; i < 1024; i += 256) h[i] = 0;
        __syncthreads();
        for (int e = blockIdx.x * 256 + t; e < E; e += 512 * 256)
            atomicAdd(&h[dst[e] >> BUCKET_SHIFT], 1);
        __syncthreads();
        for (int i = t; i < NB; i += 256)
            if (h[i]) atomicAdd(&bucketCnt[i], h[i]);   // no return use -> pipelined
    } else {
        int i = (blockIdx.x - 512) * 256 + t;
        if (i < na) oa[i] = (_Float16)a[i];
        if (i < nb) ob[i] = (_Float16)b[i];
        if (i < nc) oc[i] = (_Float16)c[i];
        if (i < 128) zrow[i] = (_Float16)0.0f;          // bufH pad row N = 0
    }
}

// one block, 1024 threads: exclusive scan of bucket counts (NB <= 1024)
__global__ void bucket_scan(const int* __restrict__ bucketCnt,
                            int* __restrict__ bucketBase, int* __restrict__ bucketCur,
                            int NB, int E) {
    __shared__ int sm[1024];
    int t = threadIdx.x;
    int v = (t < NB) ? bucketCnt[t] : 0;
    sm[t] = v;
    __syncthreads();
    for (int off = 1; off < 1024; off <<= 1) {
        int add = (t >= off) ? sm[t - off] : 0;
        __syncthreads();
        sm[t] += add;
        __syncthreads();
    }
    if (t < NB) {
        bucketBase[t] = sm[t] - v;
        bucketCur[t] = sm[t] - v;
    }
    if (t == 0) bucketBase[NB] = E;
}

// ---------------------------------------------------------------------------
// K3: blocks [0,SB) = two-level scatter of packed edge records; blocks
// [SB,...) = input-projection GEMM (column-split, independent of CSR chain).
// ---------------------------------------------------------------------------

__global__ __launch_bounds__(256)
void k_scatter_proj(const int* __restrict__ src, const int* __restrict__ dst, int E,
                    int* __restrict__ bucketCur, unsigned int* __restrict__ rec, int SB,
                    const float* __restrict__ A, const _Float16* __restrict__ W,
                    const float* __restrict__ bias, _Float16* __restrict__ Cout, int M) {
    __shared__ int hist[1024];
    __shared__ int base[1024];
    if (blockIdx.x < SB) {
        int t = threadIdx.x;
        int e0 = blockIdx.x * SCHUNK;
        int e1 = MIN(E, e0 + SCHUNK);
        for (int i = t; i < 1024; i += 256) hist[i] = 0;
        __syncthreads();
        for (int e = e0 + t; e < e1; e += 256)
            atomicAdd(&hist[dst[e] >> BUCKET_SHIFT], 1);
        __syncthreads();
        for (int i = t; i < 1024; i += 256) {
            int c = hist[i];
            base[i] = c ? atomicAdd(&bucketCur[i], c) : 0;
            hist[i] = 0;                                  // reuse as local cursor
        }
        __syncthreads();
        for (int e = e0 + t; e < e1; e += 256) {
            int d = dst[e];
            int bk = d >> BUCKET_SHIFT;
            int pos = base[bk] + atomicAdd(&hist[bk], 1); // LDS atomic, cheap
            rec[pos] = (unsigned)src[e] | ((unsigned)(d & (BUCKET_SIZE - 1)) << 16);
        }
    } else {
        int b2 = blockIdx.x - SB;
        gemm_body64<1, false, true, true, false, true, false>(
            b2 >> 1, b2 & 1, A, 128, W, 128, bias, nullptr, Cout, 128, M);
    }
}

// Pass C: one block per bucket — per-node degree, local scan, rowptr/dinv/csr fill
__global__ void bucket_build(const unsigned int* __restrict__ rec,
                             const int* __restrict__ bucketBase,
                             int* __restrict__ rowptr, unsigned short* __restrict__ csr_src,
                             float* __restrict__ dinv, int N, int E) {
    __shared__ int lcnt[256];   // only [0,64) used; padded for uniform scan
    __shared__ int sm[256];
    __shared__ int lcur[64];
    int b = blockIdx.x;
    int t = threadIdx.x;
    int beg = bucketBase[b], end = bucketBase[b + 1];
    lcnt[t] = 0;
    __syncthreads();
    for (int i = beg + t; i < end; i += 256)
        atomicAdd(&lcnt[rec[i] >> 16], 1);
    __syncthreads();
    int v = lcnt[t];
    sm[t] = v;
    __syncthreads();
    for (int off = 1; off < 256; off <<= 1) {
        int add = (t >= off) ? sm[t - off] : 0;
        __syncthreads();
        sm[t] += add;
        __syncthreads();
    }
    int excl = sm[t] - v;
    if (t < BUCKET_SIZE) {
        int node = b * BUCKET_SIZE + t;
        if (node < N) {
            rowptr[node] = beg + excl;
            dinv[node] = rsqrtf((float)(v + 1));   // self loop -> deg >= 1
        }
        lcur[t] = beg + excl;
    }
    __syncthreads();
    for (int i = beg + t; i < end; i += 256) {
        unsigned int r = rec[i];
        int pos = atomicAdd(&lcur[r >> 16], 1);
        csr_src[pos] = (unsigned short)(r & 0xFFFFu);
    }
    if (b == 0 && t == 0) rowptr[N] = E;
}

// ---------------------------------------------------------------------------
// launch
// ---------------------------------------------------------------------------

extern "C" void kernel_launch(void* const* d_in, const int* in_sizes, int n_in,
                              void* d_out, int out_size, void* d_ws, size_t ws_size,
                              hipStream_t stream) {
    const float* x     = (const float*)d_in[0];
    const int*   ei    = (const int*)d_in[1];
    const float* W_in  = (const float*)d_in[2];
    const float* b_in  = (const float*)d_in[3];
    const float* Wc    = (const float*)d_in[4];
    const float* bc    = (const float*)d_in[5];
    const float* W_out = (const float*)d_in[6];
    const float* b_out = (const float*)d_in[7];
    float* out = (float*)d_out;

    const int HID = 128;
    const int N = in_sizes[0] / HID;   // 50000
    const int E = in_sizes[1] / 2;     // 800000
    const int L = 4;
    const int* src = ei;
    const int* dst = ei + E;
    const int NB = (N + BUCKET_SIZE - 1) >> BUCKET_SHIFT;   // 782

    char* ws = (char*)d_ws;
    size_t off = 0;
    auto carve = [&](size_t bytes) {
        void* p = ws + off;
        off += (bytes + 255) & ~(size_t)255;
        return p;
    };
    float* dinv        = (float*)carve((size_t)N * 4);
    int*   rowptr      = (int*)carve((size_t)(N + 1) * 4);
    unsigned short* csr_src = (unsigned short*)carve((size_t)E * 2);
    unsigned int* rec  = (unsigned int*)carve((size_t)E * 4);
    int*   bucketCnt   = (int*)carve((size_t)1024 * 4);
    int*   bucketBase  = (int*)carve((size_t)1025 * 4);
    int*   bucketCur   = (int*)carve((size_t)1024 * 4);
    _Float16* bufA     = (_Float16*)carve((size_t)N * HID * 2);          // proj output
    _Float16* bufH     = (_Float16*)carve((size_t)(N + 1) * HID * 2);    // conv out + pad
    _Float16* bufXcat  = (_Float16*)carve((size_t)N * 512 * 2);          // concat [N,512]
    _Float16* Wf_in    = (_Float16*)carve((size_t)HID * HID * 2);
    _Float16* Wf_c     = (_Float16*)carve((size_t)L * HID * HID * 2);
    _Float16* Wf_out   = (_Float16*)carve((size_t)64 * 512 * 2);
    (void)ws_size;

    int gemm_blocks = (N + 63) / 64;           // 782 row-blocks
    int SB = (E + SCHUNK - 1) / SCHUNK;        // 391
    int AGGN = (N + 3) / 4;                    // 12500 agg node-blocks

    // ---- CSR build overlapped with weight-cvt + input projection ----
    hipMemsetAsync(bucketCnt, 0, (size_t)1024 * 4, stream);
    k_hist_cvt<<<512 + 256, 256, 0, stream>>>(
        dst, E, bucketCnt, NB,
        W_in, Wf_in, HID * HID,
        Wc, Wf_c, L * HID * HID,
        W_out, Wf_out, 64 * 512,
        bufH + (size_t)N * HID);
    bucket_scan<<<1, 1024, 0, stream>>>(bucketCnt, bucketBase, bucketCur, NB, E);
    k_scatter_proj<<<SB + 2 * gemm_blocks, 256, 0, stream>>>(
        src, dst, E, bucketCur, rec, SB,
        x, Wf_in, b_in, bufA, N);
    bucket_build<<<NB, 256, 0, stream>>>(rec, bucketBase, rowptr, csr_src, dinv, N, E);

    // ---- conv layers; aggregated X goes into bufXcat[:, l*128] ----
    for (int l = 0; l < L; ++l) {
        const void* Ain = (l == 0) ? (const void*)bufA
                                   : (const void*)(bufXcat + (size_t)(l - 1) * 128);
        int lda = (l == 0) ? 128 : 512;
        // H' = dinv[row] * (A @ Wc^T + bc)   (f16, pre-scaled rows)
        mfma_gemm64<1, true, false, true, true, true, false, true>
            <<<2 * gemm_blocks, 256, 0, stream>>>(Ain, lda, Wf_c + (size_t)l * HID * HID,
                                                  HID, bc + (size_t)l * HID, dinv,
                                                  bufH, HID, N);
        if (l < 3) {
            agg_kernel<<<AGGN, 256, 0, stream>>>((const half2_t*)bufH, dinv, rowptr,
                                                 csr_src,
                                                 (half2_t*)bufXcat + (size_t)l * 64, N);
        } else {
            // agg(3)  ||  out-partA (K = 0..384 over slabs 0-2, ready before launch)
            k_agg_out<<<AGGN + gemm_blocks, 256, 0, stream>>>(
                (const half2_t*)bufH, dinv, rowptr, csr_src,
                (half2_t*)bufXcat + (size_t)3 * 64, N, AGGN,
                bufXcat, Wf_out, b_out, out);
        }
    }

    // ---- out-partB: K = 384..512 (slab 3), fp32 accumulate into out ----
    mfma_gemm64<1, true, false, false, false, false, true, false>
        <<<gemm_blocks, 256, 0, stream>>>(bufXcat + 384, 512, Wf_out + 384, 512,
                                          nullptr, nullptr, out, 64, N);
}

// Round 12
// 309.586 us; speedup vs baseline: 1.3863x; 1.0341x over previous
//
#include <hip/hip_runtime.h>
#include <hip/hip_bf16.h>

#ifndef MIN
#define MIN(a,b) ((a)<(b)?(a):(b))
#endif

typedef _Float16 half2_t __attribute__((ext_vector_type(2)));
typedef _Float16 half4_t __attribute__((ext_vector_type(4)));
typedef _Float16 half8_t __attribute__((ext_vector_type(8)));
typedef float floatx4 __attribute__((ext_vector_type(4)));

#define BUCKET_SHIFT 6
#define BUCKET_SIZE 64
#define SCHUNK 2048

// ---------------------------------------------------------------------------
// MFMA f16 GEMM body, BN=64 (4 output col-tiles), 17KB LDS -> ~8 blocks/CU.
// A direct global->VGPR, W staged in LDS. Optional column-split: a 64-row
// tile's 128 output cols are covered by two blocks (ch = 0/1), doubling
// resident waves for the same latency (these kernels are ~97% idle).
// SCALE: multiply (acc+bias) by dinv[row] before store (pre-scaled H' rows).
// ---------------------------------------------------------------------------

template <int KCH, bool A_F16, bool RELU, bool BIAS, bool SCALE, bool F16OUT>
__device__ __forceinline__
void gemm_body64(int rb, int ch, const void* __restrict__ Av, int lda,
                 const _Float16* __restrict__ W, int ldw,
                 const float* __restrict__ bias, const float* __restrict__ dinv,
                 void* __restrict__ Cv, int ldc, int M) {
    __shared__ __align__(16) _Float16 Ws[64][136];

    int tid = threadIdx.x;
    int rowBase = rb * 64;
    int colBase = ch * 64;
    int w = tid >> 6;
    int lane = tid & 63;
    int lrow = lane & 15;
    int quad = lane >> 4;
    int kq = quad * 8;
    int gr = rowBase + w * 16 + lrow;

    floatx4 acc[4];
#pragma unroll
    for (int nt = 0; nt < 4; ++nt) acc[nt] = (floatx4){0.f, 0.f, 0.f, 0.f};

#pragma unroll
    for (int kc = 0; kc < KCH; ++kc) {
        // stage W chunk [64 x 128] for this column tile
#pragma unroll
        for (int i = tid; i < 64 * 16; i += 256) {
            int n = i >> 4, k8 = (i & 15) * 8;
            uint4 v = *(const uint4*)(W + (size_t)(colBase + n) * ldw + kc * 128 + k8);
            *(uint4*)(&Ws[n][k8]) = v;
        }
        __syncthreads();

        // A fragments: direct global loads, 16 rows x 64B per wave
        half8_t a[4];
        if (gr < M) {
            if (A_F16) {
                const _Float16* A = (const _Float16*)Av;
                const _Float16* ap = A + (size_t)gr * lda + kc * 128 + kq;
#pragma unroll
                for (int ks = 0; ks < 4; ++ks)
                    a[ks] = *(const half8_t*)(ap + ks * 32);
            } else {
                const float* A = (const float*)Av;
                const float* ap = A + (size_t)gr * lda + kc * 128 + kq;
#pragma unroll
                for (int ks = 0; ks < 4; ++ks) {
                    float4 v0 = *(const float4*)(ap + ks * 32);
                    float4 v1 = *(const float4*)(ap + ks * 32 + 4);
                    half8_t h;
                    h[0] = (_Float16)v0.x; h[1] = (_Float16)v0.y;
                    h[2] = (_Float16)v0.z; h[3] = (_Float16)v0.w;
                    h[4] = (_Float16)v1.x; h[5] = (_Float16)v1.y;
                    h[6] = (_Float16)v1.z; h[7] = (_Float16)v1.w;
                    a[ks] = h;
                }
            }
        } else {
#pragma unroll
            for (int ks = 0; ks < 4; ++ks)
                a[ks] = (half8_t){0, 0, 0, 0, 0, 0, 0, 0};
        }

#pragma unroll
        for (int ks = 0; ks < 4; ++ks) {
            int kk = ks * 32 + kq;
#pragma unroll
            for (int nt = 0; nt < 4; ++nt) {
                half8_t b = *(const half8_t*)(&Ws[nt * 16 + lrow][kk]);
                acc[nt] = __builtin_amdgcn_mfma_f32_16x16x32_f16(a[ks], b, acc[nt], 0, 0, 0);
            }
        }
        if (kc != KCH - 1) __syncthreads();
    }

#pragma unroll
    for (int nt = 0; nt < 4; ++nt) {
        int col = colBase + nt * 16 + lrow;
        float bv = BIAS ? bias[col] : 0.0f;
#pragma unroll
        for (int reg = 0; reg < 4; ++reg) {
            int gr2 = rowBase + w * 16 + quad * 4 + reg;
            if (gr2 < M) {
                float v = acc[nt][reg] + bv;
                if (RELU) v = fmaxf(v, 0.0f);
                if (SCALE) v *= dinv[gr2];
                if (F16OUT) {
                    _Float16* C = (_Float16*)Cv;
                    C[(size_t)gr2 * ldc + col] = (_Float16)v;
                } else {
                    float* C = (float*)Cv;
                    C[(size_t)gr2 * ldc + col] = v;
                }
            }
        }
    }
}

template <int KCH, bool A_F16, bool RELU, bool BIAS, bool SCALE, bool F16OUT, bool SPLIT>
__global__ __launch_bounds__(256)
void mfma_gemm64(const void* __restrict__ Av, int lda,
                 const _Float16* __restrict__ W, int ldw,
                 const float* __restrict__ bias, const float* __restrict__ dinv,
                 void* __restrict__ Cv, int ldc, int M) {
    int rb, ch;
    if (SPLIT) { rb = blockIdx.x >> 1; ch = blockIdx.x & 1; }
    else       { rb = blockIdx.x;      ch = 0; }
    gemm_body64<KCH, A_F16, RELU, BIAS, SCALE, F16OUT>(
        rb, ch, Av, lda, W, ldw, bias, dinv, Cv, ldc, M);
}

// ---------------------------------------------------------------------------
// K1: blocks [0,512) = dst histogram into buckets; blocks [512,768) = weight
// fp32->f16 conversion + zeroing of bufH pad row N.
// ---------------------------------------------------------------------------

__global__ __launch_bounds__(256)
void k_hist_cvt(const int* __restrict__ dst, int E, int* __restrict__ bucketCnt, int NB,
                const float* __restrict__ a, _Float16* __restrict__ oa, int na,
                const float* __restrict__ b, _Float16* __restrict__ ob, int nb,
                const float* __restrict__ c, _Float16* __restrict__ oc, int nc,
                _Float16* __restrict__ zrow) {
    __shared__ int h[1024];
    int t = threadIdx.x;
    if (blockIdx.x < 512) {
        for (int i = t; i < 1024; i += 256) h[i] = 0;
        __syncthreads();
        for (int e = blockIdx.x * 256 + t; e < E; e += 512 * 256)
            atomicAdd(&h[dst[e] >> BUCKET_SHIFT], 1);
        __syncthreads();
        for (int i = t; i < NB; i += 256)
            if (h[i]) atomicAdd(&bucketCnt[i], h[i]);   // no return use -> pipelined
    } else {
        int i = (blockIdx.x - 512) * 256 + t;
        if (i < na) oa[i] = (_Float16)a[i];
        if (i < nb) ob[i] = (_Float16)b[i];
        if (i < nc) oc[i] = (_Float16)c[i];
        if (i < 128) zrow[i] = (_Float16)0.0f;          // bufH pad row N = 0
    }
}

// one block, 1024 threads: exclusive scan of bucket counts (NB <= 1024)
__global__ void bucket_scan(const int* __restrict__ bucketCnt,
                            int* __restrict__ bucketBase, int* __restrict__ bucketCur,
                            int NB, int E) {
    __shared__ int sm[1024];
    int t = threadIdx.x;
    int v = (t < NB) ? bucketCnt[t] : 0;
    sm[t] = v;
    __syncthreads();
    for (int off = 1; off < 1024; off <<= 1) {
        int add = (t >= off) ? sm[t - off] : 0;
        __syncthreads();
        sm[t] += add;
        __syncthreads();
    }
    if (t < NB) {
        bucketBase[t] = sm[t] - v;
        bucketCur[t] = sm[t] - v;
    }
    if (t == 0) bucketBase[NB] = E;
}

// ---------------------------------------------------------------------------
// K3: blocks [0,SB) = two-level scatter of packed edge records; blocks
// [SB,...) = input-projection GEMM (column-split, independent of CSR chain).
// ---------------------------------------------------------------------------

__global__ __launch_bounds__(256)
void k_scatter_proj(const int* __restrict__ src, const int* __restrict__ dst, int E,
                    int* __restrict__ bucketCur, unsigned int* __restrict__ rec, int SB,
                    const float* __restrict__ A, const _Float16* __restrict__ W,
                    const float* __restrict__ bias, _Float16* __restrict__ Cout, int M) {
    __shared__ int hist[1024];
    __shared__ int base[1024];
    if (blockIdx.x < SB) {
        int t = threadIdx.x;
        int e0 = blockIdx.x * SCHUNK;
        int e1 = MIN(E, e0 + SCHUNK);
        for (int i = t; i < 1024; i += 256) hist[i] = 0;
        __syncthreads();
        for (int e = e0 + t; e < e1; e += 256)
            atomicAdd(&hist[dst[e] >> BUCKET_SHIFT], 1);
        __syncthreads();
        for (int i = t; i < 1024; i += 256) {
            int c = hist[i];
            base[i] = c ? atomicAdd(&bucketCur[i], c) : 0;
            hist[i] = 0;                                  // reuse as local cursor
        }
        __syncthreads();
        for (int e = e0 + t; e < e1; e += 256) {
            int d = dst[e];
            int bk = d >> BUCKET_SHIFT;
            int pos = base[bk] + atomicAdd(&hist[bk], 1); // LDS atomic, cheap
            rec[pos] = (unsigned)src[e] | ((unsigned)(d & (BUCKET_SIZE - 1)) << 16);
        }
    } else {
        int b2 = blockIdx.x - SB;
        gemm_body64<1, false, true, true, false, true>(
            b2 >> 1, b2 & 1, A, 128, W, 128, bias, nullptr, Cout, 128, M);
    }
}

// Pass C: one block per bucket — per-node degree, local scan, rowptr/dinv/csr fill
__global__ void bucket_build(const unsigned int* __restrict__ rec,
                             const int* __restrict__ bucketBase,
                             int* __restrict__ rowptr, unsigned short* __restrict__ csr_src,
                             float* __restrict__ dinv, int N, int E) {
    __shared__ int lcnt[256];   // only [0,64) used; padded for uniform scan
    __shared__ int sm[256];
    __shared__ int lcur[64];
    int b = blockIdx.x;
    int t = threadIdx.x;
    int beg = bucketBase[b], end = bucketBase[b + 1];
    lcnt[t] = 0;
    __syncthreads();
    for (int i = beg + t; i < end; i += 256)
        atomicAdd(&lcnt[rec[i] >> 16], 1);
    __syncthreads();
    int v = lcnt[t];
    sm[t] = v;
    __syncthreads();
    for (int off = 1; off < 256; off <<= 1) {
        int add = (t >= off) ? sm[t - off] : 0;
        __syncthreads();
        sm[t] += add;
        __syncthreads();
    }
    int excl = sm[t] - v;
    if (t < BUCKET_SIZE) {
        int node = b * BUCKET_SIZE + t;
        if (node < N) {
            rowptr[node] = beg + excl;
            dinv[node] = rsqrtf((float)(v + 1));   // self loop -> deg >= 1
        }
        lcur[t] = beg + excl;
    }
    __syncthreads();
    for (int i = beg + t; i < end; i += 256) {
        unsigned int r = rec[i];
        int pos = atomicAdd(&lcur[r >> 16], 1);
        csr_src[pos] = (unsigned short)(r & 0xFFFFu);
    }
    if (b == 0 && t == 0) rowptr[N] = E;
}

// ---------------------------------------------------------------------------
// Aggregation over pre-scaled rows H' (H'[r] = dinv[r]*h[r], row N = zeros):
//   X[node] = relu( dinv[node] * ( H'[node] + sum_{s in nbr} H'[s] ) )
// 1 wave per node, 1 dword (2 f16 ch) per lane; 64-edge batches via shfl,
// 16 independent row gathers in flight. (R2 version — proven best.)
// ---------------------------------------------------------------------------

__global__ __launch_bounds__(256)
void agg_kernel(const half2_t* __restrict__ Hb, const float* __restrict__ dinv,
                const int* __restrict__ rowptr,
                const unsigned short* __restrict__ csr_src,
                half2_t* __restrict__ X, int N) {
    int node = blockIdx.x * 4 + (threadIdx.x >> 6);
    int t = threadIdx.x & 63;
    if (node >= N) return;
    float di = dinv[node];
    half2_t hu = Hb[(size_t)node * 64 + t];
    float2 acc;
    acc.x = (float)hu.x;
    acc.y = (float)hu.y;
    int beg = rowptr[node];
    int end = rowptr[node + 1];

    for (int base = beg; base < end; base += 64) {
        int idx = base + t;
        int s_lane = (idx < end) ? (int)csr_src[idx] : N;   // row N is zeros
        int m = end - base;
        if (m > 64) m = 64;
        int mm = (m + 15) & ~15;                            // pads add 0
        for (int j = 0; j < mm; j += 16) {
            int s[16];
#pragma unroll
            for (int k = 0; k < 16; ++k) s[k] = __shfl(s_lane, j + k);
            half2_t u[16];
#pragma unroll
            for (int k = 0; k < 16; ++k) u[k] = Hb[(size_t)s[k] * 64 + t];
#pragma unroll
            for (int k = 0; k < 16; ++k) {
                acc.x += (float)u[k].x;
                acc.y += (float)u[k].y;
            }
        }
    }
    half2_t o;
    o.x = (_Float16)fmaxf(acc.x * di, 0.0f);
    o.y = (_Float16)fmaxf(acc.y * di, 0.0f);
    X[(size_t)node * 256 + t] = o;   // ld = 512 f16, caller pre-offsets column
}

// ---------------------------------------------------------------------------
// launch
// ---------------------------------------------------------------------------

extern "C" void kernel_launch(void* const* d_in, const int* in_sizes, int n_in,
                              void* d_out, int out_size, void* d_ws, size_t ws_size,
                              hipStream_t stream) {
    const float* x     = (const float*)d_in[0];
    const int*   ei    = (const int*)d_in[1];
    const float* W_in  = (const float*)d_in[2];
    const float* b_in  = (const float*)d_in[3];
    const float* Wc    = (const float*)d_in[4];
    const float* bc    = (const float*)d_in[5];
    const float* W_out = (const float*)d_in[6];
    const float* b_out = (const float*)d_in[7];
    float* out = (float*)d_out;

    const int HID = 128;
    const int N = in_sizes[0] / HID;   // 50000
    const int E = in_sizes[1] / 2;     // 800000
    const int L = 4;
    const int* src = ei;
    const int* dst = ei + E;
    const int NB = (N + BUCKET_SIZE - 1) >> BUCKET_SHIFT;   // 782

    char* ws = (char*)d_ws;
    size_t off = 0;
    auto carve = [&](size_t bytes) {
        void* p = ws + off;
        off += (bytes + 255) & ~(size_t)255;
        return p;
    };
    float* dinv        = (float*)carve((size_t)N * 4);
    int*   rowptr      = (int*)carve((size_t)(N + 1) * 4);
    unsigned short* csr_src = (unsigned short*)carve((size_t)E * 2);
    unsigned int* rec  = (unsigned int*)carve((size_t)E * 4);
    int*   bucketCnt   = (int*)carve((size_t)1024 * 4);
    int*   bucketBase  = (int*)carve((size_t)1025 * 4);
    int*   bucketCur   = (int*)carve((size_t)1024 * 4);
    _Float16* bufA     = (_Float16*)carve((size_t)N * HID * 2);          // proj output
    _Float16* bufH     = (_Float16*)carve((size_t)(N + 1) * HID * 2);    // conv out + pad row
    _Float16* bufXcat  = (_Float16*)carve((size_t)N * 512 * 2);          // concat [N,512]
    _Float16* Wf_in    = (_Float16*)carve((size_t)HID * HID * 2);
    _Float16* Wf_c     = (_Float16*)carve((size_t)L * HID * HID * 2);
    _Float16* Wf_out   = (_Float16*)carve((size_t)64 * 512 * 2);
    (void)ws_size;

    int gemm_blocks = (N + 63) / 64;           // 782 row-blocks
    int SB = (E + SCHUNK - 1) / SCHUNK;        // 391

    // ---- CSR build overlapped with weight-cvt + input projection ----
    hipMemsetAsync(bucketCnt, 0, (size_t)1024 * 4, stream);
    k_hist_cvt<<<512 + 256, 256, 0, stream>>>(
        dst, E, bucketCnt, NB,
        W_in, Wf_in, HID * HID,
        Wc, Wf_c, L * HID * HID,
        W_out, Wf_out, 64 * 512,
        bufH + (size_t)N * HID);
    bucket_scan<<<1, 1024, 0, stream>>>(bucketCnt, bucketBase, bucketCur, NB, E);
    k_scatter_proj<<<SB + 2 * gemm_blocks, 256, 0, stream>>>(
        src, dst, E, bucketCur, rec, SB,
        x, Wf_in, b_in, bufA, N);
    bucket_build<<<NB, 256, 0, stream>>>(rec, bucketBase, rowptr, csr_src, dinv, N, E);

    // ---- conv layers; aggregated X goes into bufXcat[:, l*128] ----
    for (int l = 0; l < L; ++l) {
        const void* Ain = (l == 0) ? (const void*)bufA
                                   : (const void*)(bufXcat + (size_t)(l - 1) * 128);
        int lda = (l == 0) ? 128 : 512;
        // H' = dinv[row] * (A @ Wc^T + bc)   (f16, pre-scaled rows)
        mfma_gemm64<1, true, false, true, true, true, true>
            <<<2 * gemm_blocks, 256, 0, stream>>>(Ain, lda, Wf_c + (size_t)l * HID * HID,
                                                  HID, bc + (size_t)l * HID, dinv,
                                                  bufH, HID, N);
        agg_kernel<<<(N + 3) / 4, 256, 0, stream>>>((const half2_t*)bufH, dinv, rowptr,
                                                    csr_src,
                                                    (half2_t*)bufXcat + (size_t)l * 64, N);
    }

    // ---- single concatenated output GEMM: out = bufXcat @ W_out^T + b_out ----
    mfma_gemm64<4, true, false, true, false, false, false>
        <<<gemm_blocks, 256, 0, stream>>>(bufXcat, 512, Wf_out, 512, b_out, nullptr,
                                          out, 64, N);
}